// Round 5
// baseline (14619.370 us; speedup 1.0000x reference)
//
#include <hip/hip_runtime.h>
#include <math.h>

// B=16, S=128, H=512, V=50000, N=5, R=2, Wd=512, XI=2573
#define EPSC 1e-6f
#define NBLK 256

// ws layout (float offsets)
#define OFF_H     0u         // hbuf[2][16][512]
#define OFF_R     16384u     // r[16][1024]
#define OFF_FLAGS 32768u     // arrival flags: 256 x 32 u32 (128B stride)
#define OFF_GO    40960u     // go lines:      256 x 32 u32 (128B stride)
#define STATE_END 49152u
#define OFF_XI    49152u     // xi[16][2573]
#define OFF_GX    90320u     // gates_x[128][16][2048]
#define OFF_HR    4284624u   // hr[128][16][1536]
// end 7430352 floats = 29.7 MB

__device__ __forceinline__ float sigmf(float x) { return 1.0f / (1.0f + expf(-x)); }
__device__ __forceinline__ float oneplusf(float x) {
    return 1.0f + fmaxf(x, 0.0f) + log1pf(expf(-fabsf(x)));
}

// Mailbox grid barrier, fully de-contended:
//  - arrival: each block stores gen to its own flag line
//  - block 0: thread i polls flag line i (1 poller/line), then thread i
//    stores gen to go line i (1 writer/line)
//  - each block polls ONLY its own go line (1 poller/line)
// All polls are relaxed agent-scope loads; fences only where payload flows.
__device__ __forceinline__ void gsync(unsigned* flags, unsigned* go, unsigned gen,
                                      int bi, int tid, bool rel, bool acq)
{
    __syncthreads();
    if (tid == 0) {
        if (rel) __threadfence();   // wb L2: payload reaches coherence point
        __hip_atomic_store(&flags[bi * 32], gen, __ATOMIC_RELAXED, __HIP_MEMORY_SCOPE_AGENT);
    }
    if (bi == 0) {
        unsigned v;
        do {
            v = __hip_atomic_load(&flags[tid * 32], __ATOMIC_RELAXED, __HIP_MEMORY_SCOPE_AGENT);
            if (v < gen) __builtin_amdgcn_s_sleep(1);
        } while (v < gen);
        __syncthreads();            // all 256 flags seen before any go store
        __hip_atomic_store(&go[tid * 32], gen, __ATOMIC_RELAXED, __HIP_MEMORY_SCOPE_AGENT);
    }
    if (tid == 0) {
        unsigned v;
        do {
            v = __hip_atomic_load(&go[bi * 32], __ATOMIC_RELAXED, __HIP_MEMORY_SCOPE_AGENT);
            if (v < gen) __builtin_amdgcn_s_sleep(1);
        } while (v < gen);
        if (acq) __threadfence();   // inv L2: payload reads are fresh
    }
    __syncthreads();
}

template <int K>
__device__ __forceinline__ void blk_reduce(float* v, float (*s_red)[20],
                                           float* outp, int tid)
{
#pragma unroll
    for (int i = 0; i < K; i++) {
        float x = v[i];
        for (int o = 32; o > 0; o >>= 1) x += __shfl_down(x, o, 64);
        if ((tid & 63) == 0) s_red[tid >> 6][i] = x;
    }
    __syncthreads();
    if (tid < K) outp[tid] = s_red[0][tid] + s_red[1][tid] + s_red[2][tid] + s_red[3][tid];
    __syncthreads();
}

// ---------------------------------------------------------------------------
// Persistent kernel: all 128 DNC steps. 256 blocks x 256 threads.
// ---------------------------------------------------------------------------
__global__ __launch_bounds__(256, 1) void k_main(
    const float* __restrict__ W_ih, const float* __restrict__ W_hh,
    const float* __restrict__ W_int, const float* __restrict__ b_int,
    const float* __restrict__ gx, float* __restrict__ hbuf,
    float* __restrict__ rbuf, float* __restrict__ xib,
    float* __restrict__ hr, float* __restrict__ out,
    unsigned* __restrict__ flags, unsigned* __restrict__ go)
{
    const int tid = threadIdx.x;
    const int bi  = blockIdx.x;

    // ---- LDS ----
    __shared__ __align__(16) float xin_u[9216];  // G: 4 rows x 1664 ; X: 16 rows x 576
    __shared__ float s_part[1024];
    __shared__ float c_s[32];                    // persistent c state (2 j x 16 b)
    __shared__ __align__(16) float s_M[5][520];  // persistent M (blocks 0..15)
    __shared__ float st_u[5], st_p[5], st_L[25], st_wr[10], st_ww[5];
    __shared__ float s_red[4][20];
    __shared__ float s_rb[2], s_wb, s_fg[2], s_ga, s_gw, s_pi[2][3];
    __shared__ float s_wrold[2][5], s_uu[5], s_a[5], s_wwn[5];
    __shared__ float s_pold[5], s_Lnew[25];
    __shared__ float s_zw[5], s_z[2][5], s_fw[2][5], s_bw[2][5];
    __shared__ float s_dotA[11], s_dotB[17], s_wrnew[2][5];

    // ---- persistent weight registers ----
    const int cl = tid & 7;          // gate-col 0..7 : gate=cl>>1, jl=cl&1
    const int ks = tid >> 3;         // 0..31 : k chunk of 48
    const int j0 = bi * 2;
    const int cg = (cl >> 1) * 512 + j0 + (cl & 1);
    float wl[48];
#pragma unroll
    for (int i = 0; i < 48; i++) {
        int k = ks * 48 + i;
        wl[i] = (k < 512) ? W_hh[(size_t)cg * 512 + k] : W_ih[(size_t)cg * 1536 + k];
    }
    const int xcl = tid & 15;        // xi col 0..15
    const int xks = tid >> 4;        // 0..15 : k chunk of 32
    const int q   = bi * 16 + xcl;
    const int qc  = (q < 2573) ? q : 2572;
    float wx[32];
#pragma unroll
    for (int i = 0; i < 32; i++)
        wx[i] = W_int[(size_t)(xks * 32 + i) * 2573 + qc];

    // ---- init persistent LDS state ----
    if (tid < 32) c_s[tid] = 0.f;
    if (bi < 16) {
        for (int i = tid; i < 5 * 520; i += 256) (&s_M[0][0])[i] = 0.f;
        if (tid < 5)  { st_u[tid] = 0.f; st_p[tid] = 0.f; st_ww[tid] = 0.f; }
        if (tid < 25) st_L[tid] = 0.f;
        if (tid < 10) st_wr[tid] = 0.f;
    }
    __syncthreads();

    unsigned gen = 0;

#pragma unroll 1
    for (int t = 0; t < 128; t++) {
        const float* h_in  = hbuf + (t & 1) * 8192;
        float*       h_out = hbuf + ((t + 1) & 1) * 8192;

        // ================= phase G: gates + LSTM update =================
        float gxv[4] = {0.f, 0.f, 0.f, 0.f};
        if (tid < 32) {
            int jl = tid >> 4, b = tid & 15;
            const float* g = gx + ((size_t)t * 16 + b) * 2048 + j0 + jl;
            gxv[0] = g[0]; gxv[1] = g[512]; gxv[2] = g[1024]; gxv[3] = g[1536];
        }

        float acc[16];
#pragma unroll
        for (int b = 0; b < 16; b++) acc[b] = 0.f;

#pragma unroll
        for (int bq = 0; bq < 4; bq++) {
            // stage xin (chunk-52 layout) for batches bq*4 .. bq*4+3
#pragma unroll
            for (int j2 = 0; j2 < 6; j2++) {
                int k  = tid + 256 * j2;
                int ch = k / 48;
                int off = ch * 52 + (k - ch * 48);
                if (k < 512) {
                    const float* s = h_in + k;
#pragma unroll
                    for (int b = 0; b < 4; b++) xin_u[b * 1664 + off] = s[(bq * 4 + b) * 512];
                } else {
                    const float* s = rbuf + (k - 512);
#pragma unroll
                    for (int b = 0; b < 4; b++) xin_u[b * 1664 + off] = s[(bq * 4 + b) * 1024];
                }
            }
            __syncthreads();
#pragma unroll
            for (int b = 0; b < 4; b++) {
                const float4* xp = (const float4*)&xin_u[b * 1664 + ks * 52];
#pragma unroll
                for (int i = 0; i < 12; i++) {
                    float4 xv = xp[i];
                    acc[bq * 4 + b] = fmaf(wl[4 * i + 0], xv.x, acc[bq * 4 + b]);
                    acc[bq * 4 + b] = fmaf(wl[4 * i + 1], xv.y, acc[bq * 4 + b]);
                    acc[bq * 4 + b] = fmaf(wl[4 * i + 2], xv.z, acc[bq * 4 + b]);
                    acc[bq * 4 + b] = fmaf(wl[4 * i + 3], xv.w, acc[bq * 4 + b]);
                }
            }
            __syncthreads();
        }

        // reduce over ks: lane bits 3,4,5 are ks low bits
#pragma unroll
        for (int b = 0; b < 16; b++) {
            float x = acc[b];
            x += __shfl_xor(x, 8, 64);
            x += __shfl_xor(x, 16, 64);
            x += __shfl_xor(x, 32, 64);
            acc[b] = x;
        }
        {
            int wv = tid >> 6;
            if ((tid & 63) < 8) {
#pragma unroll
                for (int b = 0; b < 16; b++) s_part[(wv * 8 + cl) * 16 + b] = acc[b];
            }
        }
        __syncthreads();
        if (tid < 32) {
            int jl = tid >> 4, b = tid & 15;
            float gi = gxv[0], gf = gxv[1], gg = gxv[2], go_ = gxv[3];
#pragma unroll
            for (int w = 0; w < 4; w++) {
                gi  += s_part[(w * 8 + 0 + jl) * 16 + b];
                gf  += s_part[(w * 8 + 2 + jl) * 16 + b];
                gg  += s_part[(w * 8 + 4 + jl) * 16 + b];
                go_ += s_part[(w * 8 + 6 + jl) * 16 + b];
            }
            float cc = sigmf(gf) * c_s[jl * 16 + b] + sigmf(gi) * tanhf(gg);
            float hh = sigmf(go_) * tanhf(cc);
            c_s[jl * 16 + b] = cc;
            int j = j0 + jl;
            h_out[b * 512 + j] = hh;
            hr[((size_t)t * 16 + b) * 1536 + j] = hh;
            if (t == 127) {
                out[1048576 + b * 512 + j] = hh;
                out[1048576 + 8192 + b * 512 + j] = cc;
            }
        }
        gen++;
        gsync(flags, go, gen, bi, tid, /*rel*/true, /*acq*/ bi < 161);

        // ================= phase X: xi = h @ W_int + b_int =================
        if (bi < 161) {
#pragma unroll
            for (int j2 = 0; j2 < 2; j2++) {
                int k = tid + 256 * j2;
                int off = (k >> 5) * 36 + (k & 31);
                const float* s = h_out + k;
#pragma unroll
                for (int b = 0; b < 16; b++) xin_u[b * 576 + off] = s[b * 512];
            }
            __syncthreads();
            float ax[16];
#pragma unroll
            for (int b = 0; b < 16; b++) ax[b] = 0.f;
#pragma unroll
            for (int b = 0; b < 16; b++) {
                const float4* hp = (const float4*)&xin_u[b * 576 + xks * 36];
#pragma unroll
                for (int i = 0; i < 8; i++) {
                    float4 hv = hp[i];
                    ax[b] = fmaf(wx[4 * i + 0], hv.x, ax[b]);
                    ax[b] = fmaf(wx[4 * i + 1], hv.y, ax[b]);
                    ax[b] = fmaf(wx[4 * i + 2], hv.z, ax[b]);
                    ax[b] = fmaf(wx[4 * i + 3], hv.w, ax[b]);
                }
            }
#pragma unroll
            for (int b = 0; b < 16; b++) {
                float x = ax[b];
                x += __shfl_xor(x, 16, 64);
                x += __shfl_xor(x, 32, 64);
                ax[b] = x;
            }
            {
                int wv = tid >> 6;
                if ((tid & 63) < 16) {
#pragma unroll
                    for (int b = 0; b < 16; b++) s_part[(wv * 16 + xcl) * 16 + b] = ax[b];
                }
            }
            __syncthreads();
            {
                int q_l = tid >> 4, b = tid & 15;
                int qq = bi * 16 + q_l;
                if (qq < 2573) {
                    float v = s_part[(0  + q_l) * 16 + b] + s_part[(16 + q_l) * 16 + b]
                            + s_part[(32 + q_l) * 16 + b] + s_part[(48 + q_l) * 16 + b]
                            + b_int[qq];
                    xib[b * 2573 + qq] = v;
                }
            }
        }
        gen++;
        gsync(flags, go, gen, bi, tid, /*rel*/ bi < 161, /*acq*/ bi < 16);

        // ================= phase M: memory machinery (blocks 0..15) =================
        if (bi < 16) {
            const float* xb = xib + bi * 2573;
            if (tid == 0) {
                s_wb = oneplusf(xb[1538]);
                s_ga = sigmf(xb[2565]);
                s_gw = sigmf(xb[2566]);
            }
            if (tid == 1 || tid == 2) {
                int rr = tid - 1;
                s_rb[rr] = oneplusf(xb[1024 + rr]);
                s_fg[rr] = sigmf(xb[2563 + rr]);
                float z0 = xb[2567 + rr * 3], z1 = xb[2568 + rr * 3], z2 = xb[2569 + rr * 3];
                float mx = fmaxf(z0, fmaxf(z1, z2));
                float e0 = expf(z0 - mx), e1 = expf(z1 - mx), e2 = expf(z2 - mx);
                float s = e0 + e1 + e2;
                s_pi[rr][0] = e0 / s; s_pi[rr][1] = e1 / s; s_pi[rr][2] = e2 / s;
            }
            if (tid >= 32 && tid < 42) { int i = tid - 32; s_wrold[i / 5][i % 5] = st_wr[i]; }
            if (tid >= 64 && tid < 69) { s_pold[tid - 64] = st_p[tid - 64]; }
            __syncthreads();
            if (tid < 5) {
                float psi = (1.f - s_fg[0] * s_wrold[0][tid]) * (1.f - s_fg[1] * s_wrold[1][tid]);
                float un = (st_u[tid] + st_ww[tid] - st_u[tid] * st_ww[tid]) * psi;
                s_uu[tid] = un; st_u[tid] = un;
            }
            __syncthreads();
            if (tid < 5) {
                float excl = 1.f;
#pragma unroll
                for (int m2 = 0; m2 < 5; m2++) {
                    bool before = (s_uu[m2] < s_uu[tid]) || (s_uu[m2] == s_uu[tid] && m2 < tid);
                    if (before) excl *= s_uu[m2];
                }
                s_a[tid] = (1.f - s_uu[tid]) * excl;
            }
            float accA[11];
#pragma unroll
            for (int i = 0; i < 11; i++) accA[i] = 0.f;
            for (int w = tid; w < 512; w += 256) {
                float wk = xb[1026 + w];
                accA[10] += wk * wk;
#pragma unroll
                for (int n = 0; n < 5; n++) {
                    float m_ = s_M[n][w];
                    accA[n]     += m_ * m_;
                    accA[5 + n] += wk * m_;
                }
            }
            blk_reduce<11>(accA, s_red, s_dotA, tid);
            if (tid < 5) {
                float sim = s_dotA[5 + tid] /
                            ((sqrtf(s_dotA[10]) + EPSC) * (sqrtf(s_dotA[tid]) + EPSC));
                s_zw[tid] = s_wb * sim;
            }
            __syncthreads();
            if (tid < 5) {
                float mx = s_zw[0];
#pragma unroll
                for (int m2 = 1; m2 < 5; m2++) mx = fmaxf(mx, s_zw[m2]);
                float sum = 0.f;
#pragma unroll
                for (int m2 = 0; m2 < 5; m2++) sum += expf(s_zw[m2] - mx);
                float cw = expf(s_zw[tid] - mx) / sum;
                float w_ = s_gw * (s_ga * s_a[tid] + (1.f - s_ga) * cw);
                s_wwn[tid] = w_; st_ww[tid] = w_;
            }
            __syncthreads();
            float accB[17];
#pragma unroll
            for (int i = 0; i < 17; i++) accB[i] = 0.f;
            for (int w = tid; w < 512; w += 256) {
                float ew = sigmf(xb[1539 + w]);
                float vw = xb[2051 + w];
                float rk0 = xb[w], rk1 = xb[512 + w];
                accB[15] += rk0 * rk0; accB[16] += rk1 * rk1;
#pragma unroll
                for (int n = 0; n < 5; n++) {
                    float m_ = s_M[n][w];
                    float mn_ = m_ * (1.f - s_wwn[n] * ew) + s_wwn[n] * vw;
                    s_M[n][w] = mn_;
                    accB[n]      += mn_ * mn_;
                    accB[5 + n]  += rk0 * mn_;
                    accB[10 + n] += rk1 * mn_;
                }
            }
            blk_reduce<17>(accB, s_red, s_dotB, tid);
            if (tid < 25) {
                int i2 = tid / 5, j2 = tid % 5;
                float Ln = (i2 == j2) ? 0.f
                         : (1.f - s_wwn[i2] - s_wwn[j2]) * st_L[tid] + s_wwn[i2] * s_pold[j2];
                s_Lnew[tid] = Ln; st_L[tid] = Ln;
            }
            __syncthreads();
            if (tid < 5) {
                float wsum = s_wwn[0] + s_wwn[1] + s_wwn[2] + s_wwn[3] + s_wwn[4];
                st_p[tid] = (1.f - wsum) * s_pold[tid] + s_wwn[tid];
            }
            if (tid < 10) {
                int rr = tid / 5, ii = tid % 5;
                float fw = 0.f, bw = 0.f;
#pragma unroll
                for (int j2 = 0; j2 < 5; j2++) {
                    fw += s_Lnew[ii * 5 + j2] * s_wrold[rr][j2];
                    bw += s_Lnew[j2 * 5 + ii] * s_wrold[rr][j2];
                }
                s_fw[rr][ii] = fw; s_bw[rr][ii] = bw;
                float sim = s_dotB[5 + rr * 5 + ii] /
                            ((sqrtf(s_dotB[15 + rr]) + EPSC) * (sqrtf(s_dotB[ii]) + EPSC));
                s_z[rr][ii] = s_rb[rr] * sim;
            }
            __syncthreads();
            if (tid < 10) {
                int rr = tid / 5, ii = tid % 5;
                float mx = s_z[rr][0];
#pragma unroll
                for (int m2 = 1; m2 < 5; m2++) mx = fmaxf(mx, s_z[rr][m2]);
                float sum = 0.f;
#pragma unroll
                for (int m2 = 0; m2 < 5; m2++) sum += expf(s_z[rr][m2] - mx);
                float cr = expf(s_z[rr][ii] - mx) / sum;
                float wn = s_pi[rr][0] * s_bw[rr][ii] + s_pi[rr][1] * cr + s_pi[rr][2] * s_fw[rr][ii];
                s_wrnew[rr][ii] = wn; st_wr[rr * 5 + ii] = wn;
            }
            __syncthreads();
            for (int idx = tid; idx < 1024; idx += 256) {
                int rr = idx >> 9, w = idx & 511;
                float rv = 0.f;
#pragma unroll
                for (int n = 0; n < 5; n++) rv += s_wrnew[rr][n] * s_M[n][w];
                rbuf[bi * 1024 + idx] = rv;
                hr[((size_t)t * 16 + bi) * 1536 + 512 + idx] = rv;
            }
        }
        gen++;
        gsync(flags, go, gen, bi, tid, /*rel*/ bi < 16, /*acq*/ true);
    }
}

// ---------------------------------------------------------------------------
// Prologue: gates_x[tok][col] = b_lstm[col] + sum_{k<512} emb[src_tok,k]*W_ih[col,k]
// ---------------------------------------------------------------------------
__global__ __launch_bounds__(256) void k_embgx(
    const int* __restrict__ src, const float* __restrict__ emb,
    const float* __restrict__ W_ih, const float* __restrict__ b_lstm,
    float* __restrict__ gx)
{
    __shared__ __align__(16) float As[16][68];
    __shared__ __align__(16) float Bs[16][68];
    const int tid = threadIdx.x;
    const int bm = blockIdx.x, bn = blockIdx.y;
    const int tm = tid >> 4, tn = tid & 15;
    float acc[4][4] = {};
    for (int k0 = 0; k0 < 512; k0 += 16) {
#pragma unroll
        for (int i = 0; i < 4; i++) {
            int idx = tid + 256 * i;
            int m = idx >> 4, kk = idx & 15;
            int tok = bm * 64 + m;
            int row = src[(tok & 15) * 128 + (tok >> 4)];
            As[kk][m] = emb[(size_t)row * 512 + k0 + kk];
        }
#pragma unroll
        for (int i = 0; i < 4; i++) {
            int idx = tid + 256 * i;
            int n = idx >> 4, kk = idx & 15;
            Bs[kk][n] = W_ih[(size_t)(bn * 64 + n) * 1536 + k0 + kk];
        }
        __syncthreads();
#pragma unroll
        for (int kk = 0; kk < 16; kk++) {
            float4 av = *(const float4*)&As[kk][tm * 4];
            float4 bv = *(const float4*)&Bs[kk][tn * 4];
            float a[4] = {av.x, av.y, av.z, av.w};
            float b[4] = {bv.x, bv.y, bv.z, bv.w};
#pragma unroll
            for (int i = 0; i < 4; i++)
#pragma unroll
                for (int j = 0; j < 4; j++) acc[i][j] = fmaf(a[i], b[j], acc[i][j]);
        }
        __syncthreads();
    }
#pragma unroll
    for (int i = 0; i < 4; i++) {
        int tok = bm * 64 + tm * 4 + i;
#pragma unroll
        for (int j = 0; j < 4; j++) {
            int col = bn * 64 + tn * 4 + j;
            gx[(size_t)tok * 2048 + col] = acc[i][j] + b_lstm[col];
        }
    }
}

// ---------------------------------------------------------------------------
// Epilogue: out[b,s,q] = b_out[q] + sum_k hr[s,b,k]*W_out[k,q]
// ---------------------------------------------------------------------------
__global__ __launch_bounds__(256) void k_out(
    const float* __restrict__ hr, const float* __restrict__ W_out,
    const float* __restrict__ b_out, float* __restrict__ out)
{
    __shared__ __align__(16) float As[16][68];
    __shared__ __align__(16) float Bs[16][68];
    const int tid = threadIdx.x;
    const int bm = blockIdx.x, bn = blockIdx.y;
    const int tm = tid >> 4, tn = tid & 15;
    float acc[4][4] = {};
    for (int k0 = 0; k0 < 1536; k0 += 16) {
#pragma unroll
        for (int i = 0; i < 4; i++) {
            int idx = tid + 256 * i;
            int m = idx >> 4, kk = idx & 15;
            As[kk][m] = hr[(size_t)(bm * 64 + m) * 1536 + k0 + kk];
        }
#pragma unroll
        for (int i = 0; i < 4; i++) {
            int idx = tid + 256 * i;
            int kk = idx >> 6, n = idx & 63;
            Bs[kk][n] = W_out[(size_t)(k0 + kk) * 512 + bn * 64 + n];
        }
        __syncthreads();
#pragma unroll
        for (int kk = 0; kk < 16; kk++) {
            float4 av = *(const float4*)&As[kk][tm * 4];
            float4 bv = *(const float4*)&Bs[kk][tn * 4];
            float a[4] = {av.x, av.y, av.z, av.w};
            float b[4] = {bv.x, bv.y, bv.z, bv.w};
#pragma unroll
            for (int i = 0; i < 4; i++)
#pragma unroll
                for (int j = 0; j < 4; j++) acc[i][j] = fmaf(a[i], b[j], acc[i][j]);
        }
        __syncthreads();
    }
#pragma unroll
    for (int i = 0; i < 4; i++) {
        int tok = bm * 64 + tm * 4 + i;
        int b_ = tok & 15, s_ = tok >> 4;
#pragma unroll
        for (int j = 0; j < 4; j++) {
            int qn = bn * 64 + tn * 4 + j;
            out[(size_t)((b_ << 7) + s_) * 512 + qn] = acc[i][j] + b_out[qn];
        }
    }
}

extern "C" void kernel_launch(void* const* d_in, const int* in_sizes, int n_in,
                              void* d_out, int out_size, void* d_ws, size_t ws_size,
                              hipStream_t stream)
{
    const int*   src    = (const int*)d_in[0];
    const float* emb    = (const float*)d_in[2];
    const float* W_ih   = (const float*)d_in[3];
    const float* W_hh   = (const float*)d_in[4];
    const float* b_lstm = (const float*)d_in[5];
    const float* W_int  = (const float*)d_in[6];
    const float* b_int  = (const float*)d_in[7];
    const float* W_out  = (const float*)d_in[8];
    const float* b_out  = (const float*)d_in[9];

    float* ws  = (float*)d_ws;
    float* out = (float*)d_out;

    float*    hbuf  = ws + OFF_H;
    float*    rbuf  = ws + OFF_R;
    unsigned* flags = (unsigned*)(ws + OFF_FLAGS);
    unsigned* go    = (unsigned*)(ws + OFF_GO);
    float*    xib   = ws + OFF_XI;
    float*    gx    = ws + OFF_GX;
    float*    hrb   = ws + OFF_HR;

    // zero recurrent state + all sync flags (deterministic across replays)
    hipMemsetAsync(ws, 0, STATE_END * sizeof(float), stream);

    // prologue: token-parallel x-part of gates (+ bias)
    k_embgx<<<dim3(32, 32), 256, 0, stream>>>(src, emb, W_ih, b_lstm, gx);

    // main sequential loop: one persistent kernel, plain launch.
    // Co-residency: 256 blocks, each <=52KB LDS & 4 waves -> every CU hosts
    // at least one; grid == CU count (verified working in rounds 3/4).
    k_main<<<dim3(NBLK), dim3(256), 0, stream>>>(
        W_ih, W_hh, W_int, b_int, gx, hbuf, rbuf, xib, hrb, out, flags, go);

    // epilogue: token-parallel output projection
    k_out<<<dim3(32, 8), 256, 0, stream>>>(hrb, W_out, b_out, out);
}

// Round 6
// 13453.699 us; speedup vs baseline: 1.0866x; 1.0866x over previous
//
#include <hip/hip_runtime.h>
#include <math.h>

// B=16, S=128, H=512, V=50000, N=5, R=2, Wd=512, XI=2573
#define EPSC 1e-6f
#define NBLK 256

// ws layout (float offsets)
#define OFF_H     0u         // hbuf[2][16][512]
#define OFF_R     16384u     // r[16][1024]
#define OFF_FLAGS 32768u     // arrival flags: 256 x 32 u32 (128B stride)
#define OFF_GO    40960u     // go lines:      256 x 32 u32 (128B stride)
#define STATE_END 49152u
#define OFF_XI    49152u     // xi[16][2573]
#define OFF_GX    90320u     // gates_x[128][16][2048]
#define OFF_HR    4284624u   // hr[128][16][1536]
// end 7430352 floats = 29.7 MB

__device__ __forceinline__ float sigmf(float x) { return 1.0f / (1.0f + expf(-x)); }
__device__ __forceinline__ float oneplusf(float x) {
    return 1.0f + fmaxf(x, 0.0f) + log1pf(expf(-fabsf(x)));
}

// Coherent (agent-scope, L1/L2-bypassing) scalar access for cross-block payload.
// Same mechanism as the barrier flags (proven coherent across XCDs in r3-r5).
// No fences anywhere -> L2 contents (weights, gx) stay hot.
__device__ __forceinline__ float gld(const float* p) {
    return __uint_as_float(__hip_atomic_load((const unsigned*)p,
                           __ATOMIC_RELAXED, __HIP_MEMORY_SCOPE_AGENT));
}
__device__ __forceinline__ void gst(float* p, float v) {
    __hip_atomic_store((unsigned*)p, __float_as_uint(v),
                       __ATOMIC_RELAXED, __HIP_MEMORY_SCOPE_AGENT);
}

// Fence-free mailbox grid barrier.
// Ordering: each wave drains its own vmem stores (s_waitcnt 0) -> ACK at
// coherence point -> __syncthreads -> flag store. Consumers order via the
// control-dependent poll loop (in-order waves, no speculation).
__device__ __forceinline__ void gsync(unsigned* flags, unsigned* go, unsigned gen,
                                      int bi, int tid)
{
    __builtin_amdgcn_s_waitcnt(0);   // drain this wave's payload stores
    __syncthreads();
    if (tid == 0)
        __hip_atomic_store(&flags[bi * 32], gen, __ATOMIC_RELAXED, __HIP_MEMORY_SCOPE_AGENT);
    if (bi == 0) {
        unsigned v;
        do {
            v = __hip_atomic_load(&flags[tid * 32], __ATOMIC_RELAXED, __HIP_MEMORY_SCOPE_AGENT);
            if (v < gen) __builtin_amdgcn_s_sleep(1);
        } while (v < gen);
        __syncthreads();             // all 256 flags seen before any go store
        __hip_atomic_store(&go[tid * 32], gen, __ATOMIC_RELAXED, __HIP_MEMORY_SCOPE_AGENT);
    }
    if (tid == 0) {
        unsigned v;
        do {
            v = __hip_atomic_load(&go[bi * 32], __ATOMIC_RELAXED, __HIP_MEMORY_SCOPE_AGENT);
            if (v < gen) __builtin_amdgcn_s_sleep(1);
        } while (v < gen);
    }
    __syncthreads();
}

template <int K>
__device__ __forceinline__ void blk_reduce(float* v, float (*s_red)[20],
                                           float* outp, int tid)
{
#pragma unroll
    for (int i = 0; i < K; i++) {
        float x = v[i];
        for (int o = 32; o > 0; o >>= 1) x += __shfl_down(x, o, 64);
        if ((tid & 63) == 0) s_red[tid >> 6][i] = x;
    }
    __syncthreads();
    if (tid < K) outp[tid] = s_red[0][tid] + s_red[1][tid] + s_red[2][tid] + s_red[3][tid];
    __syncthreads();
}

// ---------------------------------------------------------------------------
// Persistent kernel: all 128 DNC steps. 256 blocks x 256 threads.
// ---------------------------------------------------------------------------
__global__ __launch_bounds__(256, 1) void k_main(
    const float* __restrict__ W_ih, const float* __restrict__ W_hh,
    const float* __restrict__ W_int, const float* __restrict__ b_int,
    const float* __restrict__ gx, float* __restrict__ hbuf,
    float* __restrict__ rbuf, float* __restrict__ xib,
    float* __restrict__ hr, float* __restrict__ out,
    unsigned* __restrict__ flags, unsigned* __restrict__ go)
{
    const int tid = threadIdx.x;
    const int bi  = blockIdx.x;

    // ---- LDS ----
    __shared__ __align__(16) float xin_u[9216];  // G: 4 rows x 1664 ; X: 16 rows x 576
    __shared__ float s_part[1024];
    __shared__ float c_s[32];                    // persistent c state (2 j x 16 b)
    __shared__ __align__(16) float s_M[5][520];  // persistent M (blocks 0..15)
    __shared__ float st_u[5], st_p[5], st_L[25], st_wr[10], st_ww[5];
    __shared__ float s_red[4][20];
    __shared__ float s_rb[2], s_wb, s_fg[2], s_ga, s_gw, s_pi[2][3];
    __shared__ float s_wrold[2][5], s_uu[5], s_a[5], s_wwn[5];
    __shared__ float s_pold[5], s_Lnew[25];
    __shared__ float s_zw[5], s_z[2][5], s_fw[2][5], s_bw[2][5];
    __shared__ float s_dotA[11], s_dotB[17], s_wrnew[2][5];

    // ---- persistent weight registers ----
    const int cl = tid & 7;          // gate-col 0..7 : gate=cl>>1, jl=cl&1
    const int ks = tid >> 3;         // 0..31 : k chunk of 48
    const int j0 = bi * 2;
    const int cg = (cl >> 1) * 512 + j0 + (cl & 1);
    float wl[48];
#pragma unroll
    for (int i = 0; i < 48; i++) {
        int k = ks * 48 + i;
        wl[i] = (k < 512) ? W_hh[(size_t)cg * 512 + k] : W_ih[(size_t)cg * 1536 + k];
    }
    const int xcl = tid & 15;        // xi col 0..15
    const int xks = tid >> 4;        // 0..15 : k chunk of 32
    const int q   = bi * 16 + xcl;
    const int qc  = (q < 2573) ? q : 2572;
    float wx[32];
#pragma unroll
    for (int i = 0; i < 32; i++)
        wx[i] = W_int[(size_t)(xks * 32 + i) * 2573 + qc];

    // ---- init persistent LDS state ----
    if (tid < 32) c_s[tid] = 0.f;
    if (bi < 16) {
        for (int i = tid; i < 5 * 520; i += 256) (&s_M[0][0])[i] = 0.f;
        if (tid < 5)  { st_u[tid] = 0.f; st_p[tid] = 0.f; st_ww[tid] = 0.f; }
        if (tid < 25) st_L[tid] = 0.f;
        if (tid < 10) st_wr[tid] = 0.f;
    }
    __syncthreads();

    unsigned gen = 0;

#pragma unroll 1
    for (int t = 0; t < 128; t++) {
        const float* h_in  = hbuf + (t & 1) * 8192;
        float*       h_out = hbuf + ((t + 1) & 1) * 8192;

        // ================= phase G: gates + LSTM update =================
        float gxv[4] = {0.f, 0.f, 0.f, 0.f};
        if (tid < 32) {
            int jl = tid >> 4, b = tid & 15;
            const float* g = gx + ((size_t)t * 16 + b) * 2048 + j0 + jl;
            gxv[0] = g[0]; gxv[1] = g[512]; gxv[2] = g[1024]; gxv[3] = g[1536];
        }

        float acc[16];
#pragma unroll
        for (int b = 0; b < 16; b++) acc[b] = 0.f;

#pragma unroll
        for (int bq = 0; bq < 4; bq++) {
            // stage xin (chunk-52 layout) for batches bq*4 .. bq*4+3  [coherent]
#pragma unroll
            for (int j2 = 0; j2 < 6; j2++) {
                int k  = tid + 256 * j2;
                int ch = k / 48;
                int off = ch * 52 + (k - ch * 48);
                if (k < 512) {
                    const float* s = h_in + k;
#pragma unroll
                    for (int b = 0; b < 4; b++)
                        xin_u[b * 1664 + off] = gld(s + (bq * 4 + b) * 512);
                } else {
                    const float* s = rbuf + (k - 512);
#pragma unroll
                    for (int b = 0; b < 4; b++)
                        xin_u[b * 1664 + off] = gld(s + (bq * 4 + b) * 1024);
                }
            }
            __syncthreads();
#pragma unroll
            for (int b = 0; b < 4; b++) {
                const float4* xp = (const float4*)&xin_u[b * 1664 + ks * 52];
#pragma unroll
                for (int i = 0; i < 12; i++) {
                    float4 xv = xp[i];
                    acc[bq * 4 + b] = fmaf(wl[4 * i + 0], xv.x, acc[bq * 4 + b]);
                    acc[bq * 4 + b] = fmaf(wl[4 * i + 1], xv.y, acc[bq * 4 + b]);
                    acc[bq * 4 + b] = fmaf(wl[4 * i + 2], xv.z, acc[bq * 4 + b]);
                    acc[bq * 4 + b] = fmaf(wl[4 * i + 3], xv.w, acc[bq * 4 + b]);
                }
            }
            __syncthreads();
        }

        // reduce over ks: lane bits 3,4,5 are ks low bits
#pragma unroll
        for (int b = 0; b < 16; b++) {
            float x = acc[b];
            x += __shfl_xor(x, 8, 64);
            x += __shfl_xor(x, 16, 64);
            x += __shfl_xor(x, 32, 64);
            acc[b] = x;
        }
        {
            int wv = tid >> 6;
            if ((tid & 63) < 8) {
#pragma unroll
                for (int b = 0; b < 16; b++) s_part[(wv * 8 + cl) * 16 + b] = acc[b];
            }
        }
        __syncthreads();
        if (tid < 32) {
            int jl = tid >> 4, b = tid & 15;
            float gi = gxv[0], gf = gxv[1], gg = gxv[2], go_ = gxv[3];
#pragma unroll
            for (int w = 0; w < 4; w++) {
                gi  += s_part[(w * 8 + 0 + jl) * 16 + b];
                gf  += s_part[(w * 8 + 2 + jl) * 16 + b];
                gg  += s_part[(w * 8 + 4 + jl) * 16 + b];
                go_ += s_part[(w * 8 + 6 + jl) * 16 + b];
            }
            float cc = sigmf(gf) * c_s[jl * 16 + b] + sigmf(gi) * tanhf(gg);
            float hh = sigmf(go_) * tanhf(cc);
            c_s[jl * 16 + b] = cc;
            int j = j0 + jl;
            gst(h_out + b * 512 + j, hh);                       // coherent
            hr[((size_t)t * 16 + b) * 1536 + j] = hh;           // cached (post-kernel)
            if (t == 127) {
                out[1048576 + b * 512 + j] = hh;
                out[1048576 + 8192 + b * 512 + j] = cc;
            }
        }
        gen++;
        gsync(flags, go, gen, bi, tid);

        // ================= phase X: xi = h @ W_int + b_int =================
        if (bi < 161) {
#pragma unroll
            for (int j2 = 0; j2 < 2; j2++) {
                int k = tid + 256 * j2;
                int off = (k >> 5) * 36 + (k & 31);
                const float* s = h_out + k;
#pragma unroll
                for (int b = 0; b < 16; b++)
                    xin_u[b * 576 + off] = gld(s + b * 512);    // coherent
            }
            __syncthreads();
            float ax[16];
#pragma unroll
            for (int b = 0; b < 16; b++) ax[b] = 0.f;
#pragma unroll
            for (int b = 0; b < 16; b++) {
                const float4* hp = (const float4*)&xin_u[b * 576 + xks * 36];
#pragma unroll
                for (int i = 0; i < 8; i++) {
                    float4 hv = hp[i];
                    ax[b] = fmaf(wx[4 * i + 0], hv.x, ax[b]);
                    ax[b] = fmaf(wx[4 * i + 1], hv.y, ax[b]);
                    ax[b] = fmaf(wx[4 * i + 2], hv.z, ax[b]);
                    ax[b] = fmaf(wx[4 * i + 3], hv.w, ax[b]);
                }
            }
#pragma unroll
            for (int b = 0; b < 16; b++) {
                float x = ax[b];
                x += __shfl_xor(x, 16, 64);
                x += __shfl_xor(x, 32, 64);
                ax[b] = x;
            }
            {
                int wv = tid >> 6;
                if ((tid & 63) < 16) {
#pragma unroll
                    for (int b = 0; b < 16; b++) s_part[(wv * 16 + xcl) * 16 + b] = ax[b];
                }
            }
            __syncthreads();
            {
                int q_l = tid >> 4, b = tid & 15;
                int qq = bi * 16 + q_l;
                if (qq < 2573) {
                    float v = s_part[(0  + q_l) * 16 + b] + s_part[(16 + q_l) * 16 + b]
                            + s_part[(32 + q_l) * 16 + b] + s_part[(48 + q_l) * 16 + b]
                            + b_int[qq];
                    gst(&xib[b * 2573 + qq], v);                // coherent
                }
            }
        }
        gen++;
        gsync(flags, go, gen, bi, tid);

        // ================= phase M: memory machinery (blocks 0..15) =================
        if (bi < 16) {
            const float* xb = xib + bi * 2573;
            if (tid == 0) {
                s_wb = oneplusf(gld(xb + 1538));
                s_ga = sigmf(gld(xb + 2565));
                s_gw = sigmf(gld(xb + 2566));
            }
            if (tid == 1 || tid == 2) {
                int rr = tid - 1;
                s_rb[rr] = oneplusf(gld(xb + 1024 + rr));
                s_fg[rr] = sigmf(gld(xb + 2563 + rr));
                float z0 = gld(xb + 2567 + rr * 3);
                float z1 = gld(xb + 2568 + rr * 3);
                float z2 = gld(xb + 2569 + rr * 3);
                float mx = fmaxf(z0, fmaxf(z1, z2));
                float e0 = expf(z0 - mx), e1 = expf(z1 - mx), e2 = expf(z2 - mx);
                float s = e0 + e1 + e2;
                s_pi[rr][0] = e0 / s; s_pi[rr][1] = e1 / s; s_pi[rr][2] = e2 / s;
            }
            if (tid >= 32 && tid < 42) { int i = tid - 32; s_wrold[i / 5][i % 5] = st_wr[i]; }
            if (tid >= 64 && tid < 69) { s_pold[tid - 64] = st_p[tid - 64]; }
            __syncthreads();
            if (tid < 5) {
                float psi = (1.f - s_fg[0] * s_wrold[0][tid]) * (1.f - s_fg[1] * s_wrold[1][tid]);
                float un = (st_u[tid] + st_ww[tid] - st_u[tid] * st_ww[tid]) * psi;
                s_uu[tid] = un; st_u[tid] = un;
            }
            __syncthreads();
            if (tid < 5) {
                float excl = 1.f;
#pragma unroll
                for (int m2 = 0; m2 < 5; m2++) {
                    bool before = (s_uu[m2] < s_uu[tid]) || (s_uu[m2] == s_uu[tid] && m2 < tid);
                    if (before) excl *= s_uu[m2];
                }
                s_a[tid] = (1.f - s_uu[tid]) * excl;
            }
            float accA[11];
#pragma unroll
            for (int i = 0; i < 11; i++) accA[i] = 0.f;
            for (int w = tid; w < 512; w += 256) {
                float wk = gld(xb + 1026 + w);
                accA[10] += wk * wk;
#pragma unroll
                for (int n = 0; n < 5; n++) {
                    float m_ = s_M[n][w];
                    accA[n]     += m_ * m_;
                    accA[5 + n] += wk * m_;
                }
            }
            blk_reduce<11>(accA, s_red, s_dotA, tid);
            if (tid < 5) {
                float sim = s_dotA[5 + tid] /
                            ((sqrtf(s_dotA[10]) + EPSC) * (sqrtf(s_dotA[tid]) + EPSC));
                s_zw[tid] = s_wb * sim;
            }
            __syncthreads();
            if (tid < 5) {
                float mx = s_zw[0];
#pragma unroll
                for (int m2 = 1; m2 < 5; m2++) mx = fmaxf(mx, s_zw[m2]);
                float sum = 0.f;
#pragma unroll
                for (int m2 = 0; m2 < 5; m2++) sum += expf(s_zw[m2] - mx);
                float cw = expf(s_zw[tid] - mx) / sum;
                float w_ = s_gw * (s_ga * s_a[tid] + (1.f - s_ga) * cw);
                s_wwn[tid] = w_; st_ww[tid] = w_;
            }
            __syncthreads();
            float accB[17];
#pragma unroll
            for (int i = 0; i < 17; i++) accB[i] = 0.f;
            for (int w = tid; w < 512; w += 256) {
                float ew = sigmf(gld(xb + 1539 + w));
                float vw = gld(xb + 2051 + w);
                float rk0 = gld(xb + w), rk1 = gld(xb + 512 + w);
                accB[15] += rk0 * rk0; accB[16] += rk1 * rk1;
#pragma unroll
                for (int n = 0; n < 5; n++) {
                    float m_ = s_M[n][w];
                    float mn_ = m_ * (1.f - s_wwn[n] * ew) + s_wwn[n] * vw;
                    s_M[n][w] = mn_;
                    accB[n]      += mn_ * mn_;
                    accB[5 + n]  += rk0 * mn_;
                    accB[10 + n] += rk1 * mn_;
                }
            }
            blk_reduce<17>(accB, s_red, s_dotB, tid);
            if (tid < 25) {
                int i2 = tid / 5, j2 = tid % 5;
                float Ln = (i2 == j2) ? 0.f
                         : (1.f - s_wwn[i2] - s_wwn[j2]) * st_L[tid] + s_wwn[i2] * s_pold[j2];
                s_Lnew[tid] = Ln; st_L[tid] = Ln;
            }
            __syncthreads();
            if (tid < 5) {
                float wsum = s_wwn[0] + s_wwn[1] + s_wwn[2] + s_wwn[3] + s_wwn[4];
                st_p[tid] = (1.f - wsum) * s_pold[tid] + s_wwn[tid];
            }
            if (tid < 10) {
                int rr = tid / 5, ii = tid % 5;
                float fw = 0.f, bw = 0.f;
#pragma unroll
                for (int j2 = 0; j2 < 5; j2++) {
                    fw += s_Lnew[ii * 5 + j2] * s_wrold[rr][j2];
                    bw += s_Lnew[j2 * 5 + ii] * s_wrold[rr][j2];
                }
                s_fw[rr][ii] = fw; s_bw[rr][ii] = bw;
                float sim = s_dotB[5 + rr * 5 + ii] /
                            ((sqrtf(s_dotB[15 + rr]) + EPSC) * (sqrtf(s_dotB[ii]) + EPSC));
                s_z[rr][ii] = s_rb[rr] * sim;
            }
            __syncthreads();
            if (tid < 10) {
                int rr = tid / 5, ii = tid % 5;
                float mx = s_z[rr][0];
#pragma unroll
                for (int m2 = 1; m2 < 5; m2++) mx = fmaxf(mx, s_z[rr][m2]);
                float sum = 0.f;
#pragma unroll
                for (int m2 = 0; m2 < 5; m2++) sum += expf(s_z[rr][m2] - mx);
                float cr = expf(s_z[rr][ii] - mx) / sum;
                float wn = s_pi[rr][0] * s_bw[rr][ii] + s_pi[rr][1] * cr + s_pi[rr][2] * s_fw[rr][ii];
                s_wrnew[rr][ii] = wn; st_wr[rr * 5 + ii] = wn;
            }
            __syncthreads();
            for (int idx = tid; idx < 1024; idx += 256) {
                int rr = idx >> 9, w = idx & 511;
                float rv = 0.f;
#pragma unroll
                for (int n = 0; n < 5; n++) rv += s_wrnew[rr][n] * s_M[n][w];
                gst(&rbuf[bi * 1024 + idx], rv);                // coherent
                hr[((size_t)t * 16 + bi) * 1536 + 512 + idx] = rv;
            }
        }
        gen++;
        gsync(flags, go, gen, bi, tid);
    }
}

// ---------------------------------------------------------------------------
// Prologue: gates_x[tok][col] = b_lstm[col] + sum_{k<512} emb[src_tok,k]*W_ih[col,k]
// ---------------------------------------------------------------------------
__global__ __launch_bounds__(256) void k_embgx(
    const int* __restrict__ src, const float* __restrict__ emb,
    const float* __restrict__ W_ih, const float* __restrict__ b_lstm,
    float* __restrict__ gx)
{
    __shared__ __align__(16) float As[16][68];
    __shared__ __align__(16) float Bs[16][68];
    const int tid = threadIdx.x;
    const int bm = blockIdx.x, bn = blockIdx.y;
    const int tm = tid >> 4, tn = tid & 15;
    float acc[4][4] = {};
    for (int k0 = 0; k0 < 512; k0 += 16) {
#pragma unroll
        for (int i = 0; i < 4; i++) {
            int idx = tid + 256 * i;
            int m = idx >> 4, kk = idx & 15;
            int tok = bm * 64 + m;
            int row = src[(tok & 15) * 128 + (tok >> 4)];
            As[kk][m] = emb[(size_t)row * 512 + k0 + kk];
        }
#pragma unroll
        for (int i = 0; i < 4; i++) {
            int idx = tid + 256 * i;
            int n = idx >> 4, kk = idx & 15;
            Bs[kk][n] = W_ih[(size_t)(bn * 64 + n) * 1536 + k0 + kk];
        }
        __syncthreads();
#pragma unroll
        for (int kk = 0; kk < 16; kk++) {
            float4 av = *(const float4*)&As[kk][tm * 4];
            float4 bv = *(const float4*)&Bs[kk][tn * 4];
            float a[4] = {av.x, av.y, av.z, av.w};
            float b[4] = {bv.x, bv.y, bv.z, bv.w};
#pragma unroll
            for (int i = 0; i < 4; i++)
#pragma unroll
                for (int j = 0; j < 4; j++) acc[i][j] = fmaf(a[i], b[j], acc[i][j]);
        }
        __syncthreads();
    }
#pragma unroll
    for (int i = 0; i < 4; i++) {
        int tok = bm * 64 + tm * 4 + i;
#pragma unroll
        for (int j = 0; j < 4; j++) {
            int col = bn * 64 + tn * 4 + j;
            gx[(size_t)tok * 2048 + col] = acc[i][j] + b_lstm[col];
        }
    }
}

// ---------------------------------------------------------------------------
// Epilogue: out[b,s,q] = b_out[q] + sum_k hr[s,b,k]*W_out[k,q]
// ---------------------------------------------------------------------------
__global__ __launch_bounds__(256) void k_out(
    const float* __restrict__ hr, const float* __restrict__ W_out,
    const float* __restrict__ b_out, float* __restrict__ out)
{
    __shared__ __align__(16) float As[16][68];
    __shared__ __align__(16) float Bs[16][68];
    const int tid = threadIdx.x;
    const int bm = blockIdx.x, bn = blockIdx.y;
    const int tm = tid >> 4, tn = tid & 15;
    float acc[4][4] = {};
    for (int k0 = 0; k0 < 1536; k0 += 16) {
#pragma unroll
        for (int i = 0; i < 4; i++) {
            int idx = tid + 256 * i;
            int m = idx >> 4, kk = idx & 15;
            As[kk][m] = hr[(size_t)(bm * 64 + m) * 1536 + k0 + kk];
        }
#pragma unroll
        for (int i = 0; i < 4; i++) {
            int idx = tid + 256 * i;
            int kk = idx >> 6, n = idx & 63;
            Bs[kk][n] = W_out[(size_t)(k0 + kk) * 512 + bn * 64 + n];
        }
        __syncthreads();
#pragma unroll
        for (int kk = 0; kk < 16; kk++) {
            float4 av = *(const float4*)&As[kk][tm * 4];
            float4 bv = *(const float4*)&Bs[kk][tn * 4];
            float a[4] = {av.x, av.y, av.z, av.w};
            float b[4] = {bv.x, bv.y, bv.z, bv.w};
#pragma unroll
            for (int i = 0; i < 4; i++)
#pragma unroll
                for (int j = 0; j < 4; j++) acc[i][j] = fmaf(a[i], b[j], acc[i][j]);
        }
        __syncthreads();
    }
#pragma unroll
    for (int i = 0; i < 4; i++) {
        int tok = bm * 64 + tm * 4 + i;
        int b_ = tok & 15, s_ = tok >> 4;
#pragma unroll
        for (int j = 0; j < 4; j++) {
            int qn = bn * 64 + tn * 4 + j;
            out[(size_t)((b_ << 7) + s_) * 512 + qn] = acc[i][j] + b_out[qn];
        }
    }
}

extern "C" void kernel_launch(void* const* d_in, const int* in_sizes, int n_in,
                              void* d_out, int out_size, void* d_ws, size_t ws_size,
                              hipStream_t stream)
{
    const int*   src    = (const int*)d_in[0];
    const float* emb    = (const float*)d_in[2];
    const float* W_ih   = (const float*)d_in[3];
    const float* W_hh   = (const float*)d_in[4];
    const float* b_lstm = (const float*)d_in[5];
    const float* W_int  = (const float*)d_in[6];
    const float* b_int  = (const float*)d_in[7];
    const float* W_out  = (const float*)d_in[8];
    const float* b_out  = (const float*)d_in[9];

    float* ws  = (float*)d_ws;
    float* out = (float*)d_out;

    float*    hbuf  = ws + OFF_H;
    float*    rbuf  = ws + OFF_R;
    unsigned* flags = (unsigned*)(ws + OFF_FLAGS);
    unsigned* go    = (unsigned*)(ws + OFF_GO);
    float*    xib   = ws + OFF_XI;
    float*    gx    = ws + OFF_GX;
    float*    hrb   = ws + OFF_HR;

    // zero recurrent state + all sync flags (deterministic across replays)
    hipMemsetAsync(ws, 0, STATE_END * sizeof(float), stream);

    // prologue: token-parallel x-part of gates (+ bias)
    k_embgx<<<dim3(32, 32), 256, 0, stream>>>(src, emb, W_ih, b_lstm, gx);

    // main sequential loop: one persistent kernel, plain launch.
    // Co-residency: 256 blocks, each <=52KB LDS & 4 waves -> every CU hosts
    // at least one; grid == CU count (verified working in rounds 3-5).
    k_main<<<dim3(NBLK), dim3(256), 0, stream>>>(
        W_ih, W_hh, W_int, b_int, gx, hbuf, rbuf, xib, hrb, out, flags, go);

    // epilogue: token-parallel output projection
    k_out<<<dim3(32, 8), 256, 0, stream>>>(hrb, W_out, b_out, out);
}

// Round 7
// 4440.114 us; speedup vs baseline: 3.2926x; 3.0300x over previous
//
#include <hip/hip_runtime.h>
#include <math.h>

// B=16, S=128, H=512, V=50000, N=5, R=2, Wd=512, XI=2573
#define EPSC 1e-6f
#define NBLK 128

// ws layout (float offsets)
#define OFF_H     0u         // hbuf[2][16][512]
#define OFF_R     16384u     // r[16][1024]
#define OFF_FLAGS 32768u     // arrival flags: 128 x 32 u32
#define OFF_GO    36864u     // go lines:      128 x 32 u32
#define STATE_END 40960u
#define OFF_XI    40960u     // xi[16][3072] (padded rows)
#define OFF_GX    90112u     // gates_x[128][16][2048]
#define OFF_HR    4284416u   // hr[128][16][1536]
// end 7430144 floats = 29.7 MB

typedef float f32x4 __attribute__((ext_vector_type(4)));

__device__ __forceinline__ float sigmf(float x) { return 1.0f / (1.0f + expf(-x)); }
__device__ __forceinline__ float oneplusf(float x) {
    return 1.0f + fmaxf(x, 0.0f) + log1pf(expf(-fabsf(x)));
}

// coherent scalar store (agent scope, bypasses L1/L2) — proven r3-r6
__device__ __forceinline__ void gst(float* p, float v) {
    __hip_atomic_store((unsigned*)p, __float_as_uint(v),
                       __ATOMIC_RELAXED, __HIP_MEMORY_SCOPE_AGENT);
}

// Batched coherent vector loads: N global_load_dwordx4 sc0 sc1 issued
// back-to-back in ONE asm block, single waitcnt. Pipelined; L1/L2 bypass.
__device__ __forceinline__ void cld12(
    f32x4& d0, f32x4& d1, f32x4& d2, f32x4& d3, f32x4& d4, f32x4& d5,
    f32x4& d6, f32x4& d7, f32x4& d8, f32x4& d9, f32x4& d10, f32x4& d11,
    const float* p0, const float* p1, const float* p2, const float* p3,
    const float* p4, const float* p5, const float* p6, const float* p7,
    const float* p8, const float* p9, const float* p10, const float* p11)
{
    asm volatile(
        "global_load_dwordx4 %0, %12, off sc0 sc1\n\t"
        "global_load_dwordx4 %1, %13, off sc0 sc1\n\t"
        "global_load_dwordx4 %2, %14, off sc0 sc1\n\t"
        "global_load_dwordx4 %3, %15, off sc0 sc1\n\t"
        "global_load_dwordx4 %4, %16, off sc0 sc1\n\t"
        "global_load_dwordx4 %5, %17, off sc0 sc1\n\t"
        "global_load_dwordx4 %6, %18, off sc0 sc1\n\t"
        "global_load_dwordx4 %7, %19, off sc0 sc1\n\t"
        "global_load_dwordx4 %8, %20, off sc0 sc1\n\t"
        "global_load_dwordx4 %9, %21, off sc0 sc1\n\t"
        "global_load_dwordx4 %10, %22, off sc0 sc1\n\t"
        "global_load_dwordx4 %11, %23, off sc0 sc1\n\t"
        "s_waitcnt vmcnt(0)"
        : "=&v"(d0), "=&v"(d1), "=&v"(d2), "=&v"(d3), "=&v"(d4), "=&v"(d5),
          "=&v"(d6), "=&v"(d7), "=&v"(d8), "=&v"(d9), "=&v"(d10), "=&v"(d11)
        : "v"(p0), "v"(p1), "v"(p2), "v"(p3), "v"(p4), "v"(p5),
          "v"(p6), "v"(p7), "v"(p8), "v"(p9), "v"(p10), "v"(p11)
        : "memory");
}

__device__ __forceinline__ void cld8(
    f32x4& d0, f32x4& d1, f32x4& d2, f32x4& d3,
    f32x4& d4, f32x4& d5, f32x4& d6, f32x4& d7,
    const float* p0, const float* p1, const float* p2, const float* p3,
    const float* p4, const float* p5, const float* p6, const float* p7)
{
    asm volatile(
        "global_load_dwordx4 %0, %8, off sc0 sc1\n\t"
        "global_load_dwordx4 %1, %9, off sc0 sc1\n\t"
        "global_load_dwordx4 %2, %10, off sc0 sc1\n\t"
        "global_load_dwordx4 %3, %11, off sc0 sc1\n\t"
        "global_load_dwordx4 %4, %12, off sc0 sc1\n\t"
        "global_load_dwordx4 %5, %13, off sc0 sc1\n\t"
        "global_load_dwordx4 %6, %14, off sc0 sc1\n\t"
        "global_load_dwordx4 %7, %15, off sc0 sc1\n\t"
        "s_waitcnt vmcnt(0)"
        : "=&v"(d0), "=&v"(d1), "=&v"(d2), "=&v"(d3),
          "=&v"(d4), "=&v"(d5), "=&v"(d6), "=&v"(d7)
        : "v"(p0), "v"(p1), "v"(p2), "v"(p3),
          "v"(p4), "v"(p5), "v"(p6), "v"(p7)
        : "memory");
}

__device__ __forceinline__ void cld3(
    f32x4& d0, f32x4& d1, f32x4& d2,
    const float* p0, const float* p1, const float* p2)
{
    asm volatile(
        "global_load_dwordx4 %0, %3, off sc0 sc1\n\t"
        "global_load_dwordx4 %1, %4, off sc0 sc1\n\t"
        "global_load_dwordx4 %2, %5, off sc0 sc1\n\t"
        "s_waitcnt vmcnt(0)"
        : "=&v"(d0), "=&v"(d1), "=&v"(d2)
        : "v"(p0), "v"(p1), "v"(p2)
        : "memory");
}

// Fence-free mailbox grid barrier (r6, adapted to 128 blocks).
__device__ __forceinline__ void gsync(unsigned* flags, unsigned* go, unsigned gen,
                                      int bi, int tid)
{
    __builtin_amdgcn_s_waitcnt(0);   // drain this wave's payload stores
    __syncthreads();
    if (tid == 0)
        __hip_atomic_store(&flags[bi * 32], gen, __ATOMIC_RELAXED, __HIP_MEMORY_SCOPE_AGENT);
    if (bi == 0) {
        if (tid < NBLK) {
            unsigned v;
            do {
                v = __hip_atomic_load(&flags[tid * 32], __ATOMIC_RELAXED, __HIP_MEMORY_SCOPE_AGENT);
                if (v < gen) __builtin_amdgcn_s_sleep(1);
            } while (v < gen);
        }
        __syncthreads();
        if (tid < NBLK)
            __hip_atomic_store(&go[tid * 32], gen, __ATOMIC_RELAXED, __HIP_MEMORY_SCOPE_AGENT);
    }
    if (tid == 0) {
        unsigned v;
        do {
            v = __hip_atomic_load(&go[bi * 32], __ATOMIC_RELAXED, __HIP_MEMORY_SCOPE_AGENT);
            if (v < gen) __builtin_amdgcn_s_sleep(1);
        } while (v < gen);
    }
    __syncthreads();
}

template <int K>
__device__ __forceinline__ void blk_reduce(float* v, float (*s_red)[20],
                                           float* outp, int tid)
{
#pragma unroll
    for (int i = 0; i < K; i++) {
        float x = v[i];
        for (int o = 32; o > 0; o >>= 1) x += __shfl_down(x, o, 64);
        if ((tid & 63) == 0) s_red[tid >> 6][i] = x;
    }
    __syncthreads();
    if (tid < K) outp[tid] = s_red[0][tid] + s_red[1][tid] + s_red[2][tid] + s_red[3][tid];
    __syncthreads();
}

// ---------------------------------------------------------------------------
// Persistent kernel: all 128 DNC steps. 128 blocks x 256 threads.
// Weights streamed from L2 each step (no giant register arrays -> no spill).
// ---------------------------------------------------------------------------
__global__ __launch_bounds__(256, 1) void k_main(
    const float* __restrict__ W_ih, const float* __restrict__ W_hh,
    const float* __restrict__ W_int, const float* __restrict__ b_int,
    const float* __restrict__ gx, float* __restrict__ hbuf,
    float* __restrict__ rbuf, float* __restrict__ xib,
    float* __restrict__ hr, float* __restrict__ out,
    unsigned* __restrict__ flags, unsigned* __restrict__ go)
{
    const int tid = threadIdx.x;
    const int bi  = blockIdx.x;

    // ---- LDS ----
    __shared__ __align__(16) float big_u[12288];  // xin[16][768] / h_s[16][512] / s_xi[3072]
    __shared__ float s_part[1024];                // reduce scratch (G and X)
    __shared__ float c_s[64];                     // persistent c (4 j x 16 b)
    __shared__ __align__(16) float s_M[5][520];   // persistent M (blocks 0..15)
    __shared__ float st_u[5], st_p[5], st_L[25], st_wr[10], st_ww[5];
    __shared__ float s_red[4][20];
    __shared__ float s_rb[2], s_wb, s_fg[2], s_ga, s_gw, s_pi[2][3];
    __shared__ float s_wrold[2][5], s_uu[5], s_a[5], s_wwn[5];
    __shared__ float s_pold[5], s_Lnew[25];
    __shared__ float s_zw[5], s_z[2][5], s_fw[2][5], s_bw[2][5];
    __shared__ float s_dotA[11], s_dotB[17], s_wrnew[2][5];

    // G-phase thread roles: 16 cols (c) x 16 k-chunks (ksl)
    const int cG  = tid & 15;        // local col: gate=c>>2, jl=c&3
    const int ksl = tid >> 4;        // k-chunk
    const int cg  = (cG >> 2) * 512 + bi * 4 + (cG & 3);   // global gate-col

    // ---- init persistent LDS state ----
    if (tid < 64) c_s[tid] = 0.f;
    if (bi < 16) {
        for (int i = tid; i < 5 * 520; i += 256) (&s_M[0][0])[i] = 0.f;
        if (tid < 5)  { st_u[tid] = 0.f; st_p[tid] = 0.f; st_ww[tid] = 0.f; }
        if (tid < 25) st_L[tid] = 0.f;
        if (tid < 10) st_wr[tid] = 0.f;
    }
    __syncthreads();

    unsigned gen = 0;

#pragma unroll 1
    for (int t = 0; t < 128; t++) {
        const float* h_in  = hbuf + (t & 1) * 8192;
        float*       h_out = hbuf + ((t + 1) & 1) * 8192;

        // ================= phase G: gates + LSTM update =================
        float acc[16];
#pragma unroll
        for (int b = 0; b < 16; b++) acc[b] = 0.f;

#pragma unroll 1
        for (int hf = 0; hf < 2; hf++) {
            // ---- stage xin half (16 b x 768 k) via batched coherent loads ----
            {
                const int b  = tid >> 4;
                const int sg = tid & 15;
                const float* pp[12];
#pragma unroll
                for (int i = 0; i < 12; i++) {
                    int kg = hf * 768 + sg * 4 + i * 64;
                    pp[i] = (kg < 512) ? h_in + b * 512 + kg
                                       : rbuf + b * 1024 + (kg - 512);
                }
                f32x4 d0, d1, d2, d3, d4, d5, d6, d7, d8, d9, d10, d11;
                cld12(d0, d1, d2, d3, d4, d5, d6, d7, d8, d9, d10, d11,
                      pp[0], pp[1], pp[2], pp[3], pp[4], pp[5],
                      pp[6], pp[7], pp[8], pp[9], pp[10], pp[11]);
                float* dst = &big_u[b * 768 + sg * 4];
                *(f32x4*)(dst + 0 * 64) = d0;  *(f32x4*)(dst + 1 * 64) = d1;
                *(f32x4*)(dst + 2 * 64) = d2;  *(f32x4*)(dst + 3 * 64) = d3;
                *(f32x4*)(dst + 4 * 64) = d4;  *(f32x4*)(dst + 5 * 64) = d5;
                *(f32x4*)(dst + 6 * 64) = d6;  *(f32x4*)(dst + 7 * 64) = d7;
                *(f32x4*)(dst + 8 * 64) = d8;  *(f32x4*)(dst + 9 * 64) = d9;
                *(f32x4*)(dst + 10 * 64) = d10; *(f32x4*)(dst + 11 * 64) = d11;
            }
            __syncthreads();
            // ---- compute: stream weights (cached float4) x LDS xin ----
#pragma unroll
            for (int i = 0; i < 12; i++) {
                int lc = ksl * 4 + i * 64;
                int kg = hf * 768 + lc;
                const float* wp = (kg < 512) ? W_hh + (size_t)cg * 512 + kg
                                             : W_ih + (size_t)cg * 1536 + kg;
                f32x4 wv = *(const f32x4*)wp;
#pragma unroll
                for (int b = 0; b < 16; b++) {
                    f32x4 xv = *(const f32x4*)&big_u[b * 768 + lc];
                    acc[b] = fmaf(wv[0], xv[0], acc[b]);
                    acc[b] = fmaf(wv[1], xv[1], acc[b]);
                    acc[b] = fmaf(wv[2], xv[2], acc[b]);
                    acc[b] = fmaf(wv[3], xv[3], acc[b]);
                }
            }
            __syncthreads();
        }

        // reduce over ksl: in-wave over lanes 16,32 then LDS over 4 waves
#pragma unroll
        for (int b = 0; b < 16; b++) {
            float x = acc[b];
            x += __shfl_xor(x, 16, 64);
            x += __shfl_xor(x, 32, 64);
            acc[b] = x;
        }
        {
            int wv = tid >> 6;
            if ((tid & 63) < 16) {
#pragma unroll
                for (int b = 0; b < 16; b++)
                    s_part[(wv * 16 + cG) * 16 + b] = acc[b];
            }
        }
        __syncthreads();
        {   // total per (c,b); write back into s_part[c*16+b]
            int c = tid & 15, b = tid >> 4;
            float tot = s_part[(0 * 16 + c) * 16 + b] + s_part[(1 * 16 + c) * 16 + b]
                      + s_part[(2 * 16 + c) * 16 + b] + s_part[(3 * 16 + c) * 16 + b];
            int cgc = (c >> 2) * 512 + bi * 4 + (c & 3);
            tot += gx[((size_t)t * 16 + b) * 2048 + cgc];
            s_part[c * 16 + b] = tot;
        }
        __syncthreads();
        if (tid < 64) {
            int jl = tid & 3, b = tid >> 2;
            float gi  = s_part[(0 * 4 + jl) * 16 + b];
            float gf  = s_part[(1 * 4 + jl) * 16 + b];
            float gg  = s_part[(2 * 4 + jl) * 16 + b];
            float go_ = s_part[(3 * 4 + jl) * 16 + b];
            float cc = sigmf(gf) * c_s[jl * 16 + b] + sigmf(gi) * tanhf(gg);
            float hh = sigmf(go_) * tanhf(cc);
            c_s[jl * 16 + b] = cc;
            int j = bi * 4 + jl;
            gst(h_out + b * 512 + j, hh);               // coherent
            hr[((size_t)t * 16 + b) * 1536 + j] = hh;   // cached sink
            if (t == 127) {
                out[1048576 + b * 512 + j] = hh;
                out[1048576 + 8192 + b * 512 + j] = cc;
            }
        }
        gen++;
        gsync(flags, go, gen, bi, tid);

        // ================= phase X: xi = h @ W_int + b_int =================
        {
            // stage h_out (16x512) coherently into big_u
            {
                const int b = tid >> 4, s = tid & 15;
                const float* hp = h_out + b * 512 + s * 4;
                f32x4 d0, d1, d2, d3, d4, d5, d6, d7;
                cld8(d0, d1, d2, d3, d4, d5, d6, d7,
                     hp + 0 * 64, hp + 1 * 64, hp + 2 * 64, hp + 3 * 64,
                     hp + 4 * 64, hp + 5 * 64, hp + 6 * 64, hp + 7 * 64);
                float* dst = &big_u[b * 512 + s * 4];
                *(f32x4*)(dst + 0 * 64) = d0; *(f32x4*)(dst + 1 * 64) = d1;
                *(f32x4*)(dst + 2 * 64) = d2; *(f32x4*)(dst + 3 * 64) = d3;
                *(f32x4*)(dst + 4 * 64) = d4; *(f32x4*)(dst + 5 * 64) = d5;
                *(f32x4*)(dst + 6 * 64) = d6; *(f32x4*)(dst + 7 * 64) = d7;
            }
            __syncthreads();
            const int ql  = tid & 15;
            const int kcl = tid >> 4;
#pragma unroll 1
            for (int p = 0; p < 2; p++) {
                int q0 = p * 2048 + bi * 16;
                if (p == 1 && q0 >= 2573) break;
                int q  = q0 + ql;
                int qc = (q < 2573) ? q : 2572;
                float wxr[32];
#pragma unroll
                for (int i = 0; i < 32; i++)
                    wxr[i] = W_int[(size_t)(kcl * 32 + i) * 2573 + qc];
                float ax[16];
#pragma unroll
                for (int b = 0; b < 16; b++) ax[b] = 0.f;
#pragma unroll
                for (int b = 0; b < 16; b++) {
                    const f32x4* hp = (const f32x4*)&big_u[b * 512 + kcl * 32];
#pragma unroll
                    for (int i4 = 0; i4 < 8; i4++) {
                        f32x4 hv = hp[i4];
                        ax[b] = fmaf(wxr[i4 * 4 + 0], hv[0], ax[b]);
                        ax[b] = fmaf(wxr[i4 * 4 + 1], hv[1], ax[b]);
                        ax[b] = fmaf(wxr[i4 * 4 + 2], hv[2], ax[b]);
                        ax[b] = fmaf(wxr[i4 * 4 + 3], hv[3], ax[b]);
                    }
                }
#pragma unroll
                for (int b = 0; b < 16; b++) {
                    float x = ax[b];
                    x += __shfl_xor(x, 16, 64);
                    x += __shfl_xor(x, 32, 64);
                    ax[b] = x;
                }
                {
                    int wv = tid >> 6;
                    if ((tid & 63) < 16) {
#pragma unroll
                        for (int b = 0; b < 16; b++)
                            s_part[(wv * 16 + ql) * 16 + b] = ax[b];
                    }
                }
                __syncthreads();
                {
                    int q_l = tid >> 4, b = tid & 15;
                    int qq = q0 + q_l;
                    if (qq < 2573) {
                        float v = s_part[(0 + q_l) * 16 + b] + s_part[(16 + q_l) * 16 + b]
                                + s_part[(32 + q_l) * 16 + b] + s_part[(48 + q_l) * 16 + b]
                                + b_int[qq];
                        gst(&xib[b * 3072 + qq], v);    // coherent
                    }
                }
                __syncthreads();
            }
        }
        gen++;
        gsync(flags, go, gen, bi, tid);

        // ================= phase M: memory machinery (blocks 0..15) =================
        if (bi < 16) {
            // stage this batch's xi (3072 floats incl. pad) coherently into big_u
            {
                const float* xs = xib + bi * 3072;
                f32x4 d0, d1, d2;
                cld3(d0, d1, d2,
                     xs + (tid + 0) * 4, xs + (tid + 256) * 4, xs + (tid + 512) * 4);
                *(f32x4*)&big_u[(tid + 0) * 4]   = d0;
                *(f32x4*)&big_u[(tid + 256) * 4] = d1;
                *(f32x4*)&big_u[(tid + 512) * 4] = d2;
            }
            __syncthreads();
            const float* xb = big_u;   // staged xi in LDS

            if (tid == 0) {
                s_wb = oneplusf(xb[1538]);
                s_ga = sigmf(xb[2565]);
                s_gw = sigmf(xb[2566]);
            }
            if (tid == 1 || tid == 2) {
                int rr = tid - 1;
                s_rb[rr] = oneplusf(xb[1024 + rr]);
                s_fg[rr] = sigmf(xb[2563 + rr]);
                float z0 = xb[2567 + rr * 3], z1 = xb[2568 + rr * 3], z2 = xb[2569 + rr * 3];
                float mx = fmaxf(z0, fmaxf(z1, z2));
                float e0 = expf(z0 - mx), e1 = expf(z1 - mx), e2 = expf(z2 - mx);
                float s = e0 + e1 + e2;
                s_pi[rr][0] = e0 / s; s_pi[rr][1] = e1 / s; s_pi[rr][2] = e2 / s;
            }
            if (tid >= 32 && tid < 42) { int i = tid - 32; s_wrold[i / 5][i % 5] = st_wr[i]; }
            if (tid >= 64 && tid < 69) { s_pold[tid - 64] = st_p[tid - 64]; }
            __syncthreads();
            if (tid < 5) {
                float psi = (1.f - s_fg[0] * s_wrold[0][tid]) * (1.f - s_fg[1] * s_wrold[1][tid]);
                float un = (st_u[tid] + st_ww[tid] - st_u[tid] * st_ww[tid]) * psi;
                s_uu[tid] = un; st_u[tid] = un;
            }
            __syncthreads();
            if (tid < 5) {
                float excl = 1.f;
#pragma unroll
                for (int m2 = 0; m2 < 5; m2++) {
                    bool before = (s_uu[m2] < s_uu[tid]) || (s_uu[m2] == s_uu[tid] && m2 < tid);
                    if (before) excl *= s_uu[m2];
                }
                s_a[tid] = (1.f - s_uu[tid]) * excl;
            }
            float accA[11];
#pragma unroll
            for (int i = 0; i < 11; i++) accA[i] = 0.f;
            for (int w = tid; w < 512; w += 256) {
                float wk = xb[1026 + w];
                accA[10] += wk * wk;
#pragma unroll
                for (int n = 0; n < 5; n++) {
                    float m_ = s_M[n][w];
                    accA[n]     += m_ * m_;
                    accA[5 + n] += wk * m_;
                }
            }
            blk_reduce<11>(accA, s_red, s_dotA, tid);
            if (tid < 5) {
                float sim = s_dotA[5 + tid] /
                            ((sqrtf(s_dotA[10]) + EPSC) * (sqrtf(s_dotA[tid]) + EPSC));
                s_zw[tid] = s_wb * sim;
            }
            __syncthreads();
            if (tid < 5) {
                float mx = s_zw[0];
#pragma unroll
                for (int m2 = 1; m2 < 5; m2++) mx = fmaxf(mx, s_zw[m2]);
                float sum = 0.f;
#pragma unroll
                for (int m2 = 0; m2 < 5; m2++) sum += expf(s_zw[m2] - mx);
                float cw = expf(s_zw[tid] - mx) / sum;
                float w_ = s_gw * (s_ga * s_a[tid] + (1.f - s_ga) * cw);
                s_wwn[tid] = w_; st_ww[tid] = w_;
            }
            __syncthreads();
            float accB[17];
#pragma unroll
            for (int i = 0; i < 17; i++) accB[i] = 0.f;
            for (int w = tid; w < 512; w += 256) {
                float ew = sigmf(xb[1539 + w]);
                float vw = xb[2051 + w];
                float rk0 = xb[w], rk1 = xb[512 + w];
                accB[15] += rk0 * rk0; accB[16] += rk1 * rk1;
#pragma unroll
                for (int n = 0; n < 5; n++) {
                    float m_ = s_M[n][w];
                    float mn_ = m_ * (1.f - s_wwn[n] * ew) + s_wwn[n] * vw;
                    s_M[n][w] = mn_;
                    accB[n]      += mn_ * mn_;
                    accB[5 + n]  += rk0 * mn_;
                    accB[10 + n] += rk1 * mn_;
                }
            }
            blk_reduce<17>(accB, s_red, s_dotB, tid);
            if (tid < 25) {
                int i2 = tid / 5, j2 = tid % 5;
                float Ln = (i2 == j2) ? 0.f
                         : (1.f - s_wwn[i2] - s_wwn[j2]) * st_L[tid] + s_wwn[i2] * s_pold[j2];
                s_Lnew[tid] = Ln; st_L[tid] = Ln;
            }
            __syncthreads();
            if (tid < 5) {
                float wsum = s_wwn[0] + s_wwn[1] + s_wwn[2] + s_wwn[3] + s_wwn[4];
                st_p[tid] = (1.f - wsum) * s_pold[tid] + s_wwn[tid];
            }
            if (tid < 10) {
                int rr = tid / 5, ii = tid % 5;
                float fw = 0.f, bw = 0.f;
#pragma unroll
                for (int j2 = 0; j2 < 5; j2++) {
                    fw += s_Lnew[ii * 5 + j2] * s_wrold[rr][j2];
                    bw += s_Lnew[j2 * 5 + ii] * s_wrold[rr][j2];
                }
                s_fw[rr][ii] = fw; s_bw[rr][ii] = bw;
                float sim = s_dotB[5 + rr * 5 + ii] /
                            ((sqrtf(s_dotB[15 + rr]) + EPSC) * (sqrtf(s_dotB[ii]) + EPSC));
                s_z[rr][ii] = s_rb[rr] * sim;
            }
            __syncthreads();
            if (tid < 10) {
                int rr = tid / 5, ii = tid % 5;
                float mx = s_z[rr][0];
#pragma unroll
                for (int m2 = 1; m2 < 5; m2++) mx = fmaxf(mx, s_z[rr][m2]);
                float sum = 0.f;
#pragma unroll
                for (int m2 = 0; m2 < 5; m2++) sum += expf(s_z[rr][m2] - mx);
                float cr = expf(s_z[rr][ii] - mx) / sum;
                float wn = s_pi[rr][0] * s_bw[rr][ii] + s_pi[rr][1] * cr + s_pi[rr][2] * s_fw[rr][ii];
                s_wrnew[rr][ii] = wn; st_wr[rr * 5 + ii] = wn;
            }
            __syncthreads();
            for (int idx = tid; idx < 1024; idx += 256) {
                int rr = idx >> 9, w = idx & 511;
                float rv = 0.f;
#pragma unroll
                for (int n = 0; n < 5; n++) rv += s_wrnew[rr][n] * s_M[n][w];
                gst(&rbuf[bi * 1024 + idx], rv);        // coherent
                hr[((size_t)t * 16 + bi) * 1536 + 512 + idx] = rv;
            }
        }
        gen++;
        gsync(flags, go, gen, bi, tid);
    }
}

// ---------------------------------------------------------------------------
// Prologue: gates_x[tok][col] = b_lstm[col] + sum_{k<512} emb[src_tok,k]*W_ih[col,k]
// ---------------------------------------------------------------------------
__global__ __launch_bounds__(256) void k_embgx(
    const int* __restrict__ src, const float* __restrict__ emb,
    const float* __restrict__ W_ih, const float* __restrict__ b_lstm,
    float* __restrict__ gx)
{
    __shared__ __align__(16) float As[16][68];
    __shared__ __align__(16) float Bs[16][68];
    const int tid = threadIdx.x;
    const int bm = blockIdx.x, bn = blockIdx.y;
    const int tm = tid >> 4, tn = tid & 15;
    float acc[4][4] = {};
    for (int k0 = 0; k0 < 512; k0 += 16) {
#pragma unroll
        for (int i = 0; i < 4; i++) {
            int idx = tid + 256 * i;
            int m = idx >> 4, kk = idx & 15;
            int tok = bm * 64 + m;
            int row = src[(tok & 15) * 128 + (tok >> 4)];
            As[kk][m] = emb[(size_t)row * 512 + k0 + kk];
        }
#pragma unroll
        for (int i = 0; i < 4; i++) {
            int idx = tid + 256 * i;
            int n = idx >> 4, kk = idx & 15;
            Bs[kk][n] = W_ih[(size_t)(bn * 64 + n) * 1536 + k0 + kk];
        }
        __syncthreads();
#pragma unroll
        for (int kk = 0; kk < 16; kk++) {
            float4 av = *(const float4*)&As[kk][tm * 4];
            float4 bv = *(const float4*)&Bs[kk][tn * 4];
            float a[4] = {av.x, av.y, av.z, av.w};
            float b[4] = {bv.x, bv.y, bv.z, bv.w};
#pragma unroll
            for (int i = 0; i < 4; i++)
#pragma unroll
                for (int j = 0; j < 4; j++) acc[i][j] = fmaf(a[i], b[j], acc[i][j]);
        }
        __syncthreads();
    }
#pragma unroll
    for (int i = 0; i < 4; i++) {
        int tok = bm * 64 + tm * 4 + i;
#pragma unroll
        for (int j = 0; j < 4; j++) {
            int col = bn * 64 + tn * 4 + j;
            gx[(size_t)tok * 2048 + col] = acc[i][j] + b_lstm[col];
        }
    }
}

// ---------------------------------------------------------------------------
// Epilogue: out[b,s,q] = b_out[q] + sum_k hr[s,b,k]*W_out[k,q]
// ---------------------------------------------------------------------------
__global__ __launch_bounds__(256) void k_out(
    const float* __restrict__ hr, const float* __restrict__ W_out,
    const float* __restrict__ b_out, float* __restrict__ out)
{
    __shared__ __align__(16) float As[16][68];
    __shared__ __align__(16) float Bs[16][68];
    const int tid = threadIdx.x;
    const int bm = blockIdx.x, bn = blockIdx.y;
    const int tm = tid >> 4, tn = tid & 15;
    float acc[4][4] = {};
    for (int k0 = 0; k0 < 1536; k0 += 16) {
#pragma unroll
        for (int i = 0; i < 4; i++) {
            int idx = tid + 256 * i;
            int m = idx >> 4, kk = idx & 15;
            As[kk][m] = hr[(size_t)(bm * 64 + m) * 1536 + k0 + kk];
        }
#pragma unroll
        for (int i = 0; i < 4; i++) {
            int idx = tid + 256 * i;
            int kk = idx >> 6, n = idx & 63;
            Bs[kk][n] = W_out[(size_t)(k0 + kk) * 512 + bn * 64 + n];
        }
        __syncthreads();
#pragma unroll
        for (int kk = 0; kk < 16; kk++) {
            float4 av = *(const float4*)&As[kk][tm * 4];
            float4 bv = *(const float4*)&Bs[kk][tn * 4];
            float a[4] = {av.x, av.y, av.z, av.w};
            float b[4] = {bv.x, bv.y, bv.z, bv.w};
#pragma unroll
            for (int i = 0; i < 4; i++)
#pragma unroll
                for (int j = 0; j < 4; j++) acc[i][j] = fmaf(a[i], b[j], acc[i][j]);
        }
        __syncthreads();
    }
#pragma unroll
    for (int i = 0; i < 4; i++) {
        int tok = bm * 64 + tm * 4 + i;
        int b_ = tok & 15, s_ = tok >> 4;
#pragma unroll
        for (int j = 0; j < 4; j++) {
            int qn = bn * 64 + tn * 4 + j;
            out[(size_t)((b_ << 7) + s_) * 512 + qn] = acc[i][j] + b_out[qn];
        }
    }
}

extern "C" void kernel_launch(void* const* d_in, const int* in_sizes, int n_in,
                              void* d_out, int out_size, void* d_ws, size_t ws_size,
                              hipStream_t stream)
{
    const int*   src    = (const int*)d_in[0];
    const float* emb    = (const float*)d_in[2];
    const float* W_ih   = (const float*)d_in[3];
    const float* W_hh   = (const float*)d_in[4];
    const float* b_lstm = (const float*)d_in[5];
    const float* W_int  = (const float*)d_in[6];
    const float* b_int  = (const float*)d_in[7];
    const float* W_out  = (const float*)d_in[8];
    const float* b_out  = (const float*)d_in[9];

    float* ws  = (float*)d_ws;
    float* out = (float*)d_out;

    float*    hbuf  = ws + OFF_H;
    float*    rbuf  = ws + OFF_R;
    unsigned* flags = (unsigned*)(ws + OFF_FLAGS);
    unsigned* go    = (unsigned*)(ws + OFF_GO);
    float*    xib   = ws + OFF_XI;
    float*    gx    = ws + OFF_GX;
    float*    hrb   = ws + OFF_HR;

    // zero recurrent state + all sync flags (deterministic across replays)
    hipMemsetAsync(ws, 0, STATE_END * sizeof(float), stream);

    // prologue: token-parallel x-part of gates (+ bias)
    k_embgx<<<dim3(32, 32), 256, 0, stream>>>(src, emb, W_ih, b_lstm, gx);

    // main sequential loop: one persistent kernel (128 blocks, trivially
    // co-resident on 256 CUs).
    k_main<<<dim3(NBLK), dim3(256), 0, stream>>>(
        W_ih, W_hh, W_int, b_int, gx, hbuf, rbuf, xib, hrb, out, flags, go);

    // epilogue: token-parallel output projection
    k_out<<<dim3(32, 8), 256, 0, stream>>>(hrb, W_out, b_out, out);
}